// Round 1
// baseline (3436.361 us; speedup 1.0000x reference)
//
#include <hip/hip_runtime.h>
#include <hip/hip_bf16.h>
#include <stdint.h>

typedef __bf16 bf16x8 __attribute__((ext_vector_type(8)));
typedef float f32x4 __attribute__((ext_vector_type(4)));

#define Bb 64
#define Ss 2048
#define Ff 1024
#define Hh 1024
#define Ll 128
#define NCc 16

// fp32 -> bf16 round-to-nearest-even
__device__ __forceinline__ uint16_t f2bf_rne(float x) {
    union { float f; uint32_t u; } c; c.f = x;
    uint32_t u = c.u;
    return (uint16_t)((u + 0x7FFFu + ((u >> 16) & 1u)) >> 16);
}

__device__ __forceinline__ void load_lds16(const void* g, void* l) {
    __builtin_amdgcn_global_load_lds(
        (__attribute__((address_space(1))) void*)(uintptr_t)g,
        (__attribute__((address_space(3))) void*)l, 16, 0, 0);
}

// ---------------- prep: bf16 weights, bias sum, zero h0 + barrier area ----------------
__global__ __launch_bounds__(256) void prep_kernel(
    const float* __restrict__ Wih, const float* __restrict__ Whh,
    const float* __restrict__ bih, const float* __restrict__ bhh,
    uint16_t* __restrict__ wih_bf, uint16_t* __restrict__ whh_bf,
    uint16_t* __restrict__ h0, float* __restrict__ bias,
    unsigned* __restrict__ bar)
{
    int i = blockIdx.x * 256 + threadIdx.x;   // grid 4096*256 = 1048576 exactly
    wih_bf[i] = f2bf_rne(Wih[i]);
    whh_bf[i] = f2bf_rne(Whh[i]);
    h0[i] = 0;
    if (i < Hh) bias[i] = bih[i] + bhh[i];
    if (i < 1024) bar[i] = 0u;                // 4 KB barrier area
}

// ---------------- xproj GEMM: out[map(t,n), h] = x @ Wih^T + bias
// grid (8,1024). XCD-local remap: all 8 h-blocks sharing one A-tile get the same
// linear bid%8 (= blockIdx.x) -> same XCD L2, adjacent dispatch -> A fetched ~once.
__global__ __launch_bounds__(256) void xproj_kernel(
    const float* __restrict__ x, const uint16_t* __restrict__ wih,
    const float* __restrict__ bias, float* __restrict__ out)
{
    __shared__ __bf16 As[128*32];
    __shared__ __bf16 Bs[128*32];
    const int hb = blockIdx.y & 7;
    const int mb = blockIdx.x * 128 + (blockIdx.y >> 3);
    const int tid = threadIdx.x;
    const int wave = tid >> 6, lane = tid & 63;
    const int wm = (wave >> 1) * 64, wn = (wave & 1) * 64;

    const int t  = mb >> 3;            // reversed-time index (same for whole block)
    const int n0 = (mb & 7) * 128;     // sequence-block base

    int arow[4], acol[4];
#pragma unroll
    for (int p = 0; p < 4; ++p) {
        int idx = p*256 + tid;
        int r = idx >> 3, c4 = idx & 7;
        int n = n0 + r;
        int b = n >> 4, c = n & 15;
        arow[p] = b*Ss + c*Ll + (Ll-1-t);   // reversed time within chunk
        acol[p] = c4*4;
    }

    f32x4 acc[4][4] = {};

    for (int k0 = 0; k0 < Ff; k0 += 32) {
        __syncthreads();
#pragma unroll
        for (int p = 0; p < 2; ++p) {
            int idx = p*256 + tid;
            int r = idx >> 2, c = idx & 3;
            load_lds16(wih + (size_t)(hb*128 + r)*1024 + (k0 + c*8), (char*)Bs + idx*16);
        }
#pragma unroll
        for (int p = 0; p < 4; ++p) {
            int idx = p*256 + tid;
            const float4 v = *(const float4*)(x + (size_t)arow[p]*Ff + k0 + acol[p]);
            uint32_t lo = (uint32_t)f2bf_rne(v.x) | ((uint32_t)f2bf_rne(v.y) << 16);
            uint32_t hi = (uint32_t)f2bf_rne(v.z) | ((uint32_t)f2bf_rne(v.w) << 16);
            *(uint2*)((char*)As + idx*8) = make_uint2(lo, hi);
        }
        __syncthreads();

        bf16x8 af[4], bfr[4];
#pragma unroll
        for (int i = 0; i < 4; ++i)
            af[i] = *(const bf16x8*)&As[(wm + i*16 + (lane & 15))*32 + (lane >> 4)*8];
#pragma unroll
        for (int j = 0; j < 4; ++j)
            bfr[j] = *(const bf16x8*)&Bs[(wn + j*16 + (lane & 15))*32 + (lane >> 4)*8];
#pragma unroll
        for (int i = 0; i < 4; ++i)
#pragma unroll
            for (int j = 0; j < 4; ++j)
                acc[i][j] = __builtin_amdgcn_mfma_f32_16x16x32_bf16(af[i], bfr[j], acc[i][j], 0, 0, 0);
    }

    float bsv[4]; int coln[4];
#pragma unroll
    for (int j = 0; j < 4; ++j) {
        coln[j] = hb*128 + wn + j*16 + (lane & 15);
        bsv[j] = bias[coln[j]];
    }
#pragma unroll
    for (int i = 0; i < 4; ++i) {
#pragma unroll
        for (int r = 0; r < 4; ++r) {
            int n = n0 + wm + i*16 + (lane >> 4)*4 + r;
            int b = n >> 4, c = n & 15;
            size_t orow = (size_t)b*Ss + (size_t)(NCc-1-c)*Ll + (Ll-1-t);
            float* orp = out + orow*Hh;
#pragma unroll
            for (int j = 0; j < 4; ++j)
                orp[coln[j]] = acc[i][j][r] + bsv[j];
        }
    }
}

// ---------------- fused scan: one persistent cooperative kernel, 128 steps ----------------
// 256 blocks of 256 threads, 1 block/CU (144 KB LDS). Block bid: nb = bid&15 (n-strip of
// 64 rows), hb = bid>>4 (h-strip of 64 cols). bid%8 = nb%8 -> each n-group's 16 blocks on
// one XCD. Whh strip persistent in LDS (swizzled); hprev staged per 64-K-chunk via
// global_load_lds with pre-swizzled source; per-group 16-block barrier between steps.

__device__ __forceinline__ void stage_A(const uint16_t* __restrict__ hp, int nb, int c,
                                        __bf16* dst, int tid) {
#pragma unroll
    for (int p = 0; p < 2; ++p) {
        int u = p*256 + tid;          // u in [0,512): 64 rows x 8 16B-units
        int r = u >> 3;
        int s = u & 7;
        int k = (c << 6) + ((s ^ (r & 7)) << 3);   // inverse-swizzled source column
        load_lds16(hp + ((size_t)(nb*64 + r) << 10) + k, (char*)dst + u*16);
    }
}

__global__ __launch_bounds__(256, 1) void scan_kernel(
    const uint16_t* __restrict__ whh,
    uint16_t* __restrict__ h0buf, uint16_t* __restrict__ h1buf,
    float* __restrict__ out, unsigned* __restrict__ bar)
{
    __shared__ __align__(16) __bf16 Bs[64 * 1024];   // 128 KB, persistent Whh strip
    __shared__ __align__(16) __bf16 As[2][64 * 64];  // 16 KB, double-buffered hprev chunk

    const int bid = blockIdx.x;
    const int nb = bid & 15;
    const int hb = bid >> 4;
    const int tid = threadIdx.x;
    const int lane = tid & 63;
    const int wave = tid >> 6;
    const int wm = (wave >> 1) * 32, wn = (wave & 1) * 32;  // 2x2 waves of 32x32
    const int l15 = lane & 15, l4 = lane >> 4;

    unsigned* cnt = bar + nb * 64;
    unsigned* gen = bar + nb * 64 + 32;

    // ---- load Whh strip rows [hb*64, +64), XOR-swizzled: byte_in_row ^= (row&7)<<4 ----
    for (int u = tid; u < 8192; u += 256) {     // 8192 16B-units = 128 KB
        int r = u >> 7, s = u & 127;
        int k = (s ^ (r & 7)) << 3;
        bf16x8 v = *(const bf16x8*)(whh + ((size_t)(hb*64 + r) << 10) + k);
        *(bf16x8*)((char*)Bs + u*16) = v;
    }

    // ---- per-(i,r) invariants ----
    float* orb[2][4];
    int hoff[2][4];
#pragma unroll
    for (int i = 0; i < 2; ++i)
#pragma unroll
        for (int r = 0; r < 4; ++r) {
            int n = nb*64 + wm + l4*4 + i*16 + r;
            int b = n >> 4, cch = n & 15;
            orb[i][r] = out + ((size_t)b*Ss + (size_t)(NCc-1-cch)*Ll)*Hh + hb*64;
            hoff[i][r] = n*Hh + hb*64;
        }

    __syncthreads();

#pragma unroll 1
    for (int t = 0; t < Ll; ++t) {
        const uint16_t* hp = (t & 1) ? h1buf : h0buf;
        uint16_t*       hn = (t & 1) ? h0buf : h1buf;
        const size_t toff = (size_t)(Ll-1-t) * Hh;

        // prefetch xp (xproj output) for this step's rows — block-private, overlaps K-loop
        float xpv[2][4][2];
#pragma unroll
        for (int i = 0; i < 2; ++i)
#pragma unroll
            for (int r = 0; r < 4; ++r) {
                const float* orp = orb[i][r] + toff;
                xpv[i][r][0] = orp[wn + l15];
                xpv[i][r][1] = orp[wn + 16 + l15];
            }

        f32x4 acc[2][2] = {};

        if (t > 0) {   // t==0: h0 == 0, GEMM contributes exactly 0 — skip
            stage_A(hp, nb, 0, &As[0][0], tid);
            __syncthreads();
#pragma unroll
            for (int c = 0; c < 16; ++c) {
                if (c < 15) stage_A(hp, nb, c + 1, &As[(c + 1) & 1][0], tid);
                const char* Ab = (const char*)&As[c & 1][0];
#pragma unroll
                for (int ks = 0; ks < 2; ++ks) {
                    bf16x8 af[2], bv[2];
#pragma unroll
                    for (int i = 0; i < 2; ++i) {
                        int r = wm + i*16 + l15;
                        int off = r*128 + ((ks*64 + l4*16) ^ ((r & 7) << 4));
                        af[i] = *(const bf16x8*)(Ab + off);
                    }
#pragma unroll
                    for (int j = 0; j < 2; ++j) {
                        int r = wn + j*16 + l15;
                        int off = r*2048 + ((c*128 + ks*64 + l4*16) ^ ((r & 7) << 4));
                        bv[j] = *(const bf16x8*)((const char*)Bs + off);
                    }
#pragma unroll
                    for (int i = 0; i < 2; ++i)
#pragma unroll
                        for (int j = 0; j < 2; ++j)
                            acc[i][j] = __builtin_amdgcn_mfma_f32_16x16x32_bf16(af[i], bv[j], acc[i][j], 0, 0, 0);
                }
                __syncthreads();
            }
        }

        // ---- epilogue: z = xp + acc, tanh, write out (fp32) + hnext (bf16) ----
#pragma unroll
        for (int i = 0; i < 2; ++i)
#pragma unroll
            for (int r = 0; r < 4; ++r) {
                float* orp = orb[i][r] + toff;
                uint16_t* hnp = hn + hoff[i][r];
#pragma unroll
                for (int j = 0; j < 2; ++j) {
                    int colo = wn + j*16 + l15;
                    float z = xpv[i][r][j] + acc[i][j][r];
                    float e = __expf(2.0f*z);
                    float h = 1.0f - 2.0f/(e + 1.0f);
                    orp[colo] = h;
                    hnp[colo] = f2bf_rne(h);
                    if (t == Ll-1 && r == 3 && l4 == 3) {  // n&15==15: final hidden state
                        int b = (nb*64 + wm + i*16 + 15) >> 4;
                        out[(size_t)Bb*Ss*Hh + (size_t)b*Hh + hb*64 + colo] = h;
                    }
                }
            }

        // ---- per-group barrier: 16 blocks sharing nb (agent-scope acq/rel, sense-reversing) ----
        if (t < Ll - 1) {
            __syncthreads();   // all waves' stores issued + vmcnt drained
            if (tid == 0) {
                unsigned g = __hip_atomic_load(gen, __ATOMIC_RELAXED, __HIP_MEMORY_SCOPE_AGENT);
                unsigned a = __hip_atomic_fetch_add(cnt, 1u, __ATOMIC_ACQ_REL, __HIP_MEMORY_SCOPE_AGENT);
                if (a == 15u) {
                    __hip_atomic_store(cnt, 0u, __ATOMIC_RELAXED, __HIP_MEMORY_SCOPE_AGENT);
                    __hip_atomic_store(gen, g + 1u, __ATOMIC_RELEASE, __HIP_MEMORY_SCOPE_AGENT);
                } else {
                    while (__hip_atomic_load(gen, __ATOMIC_RELAXED, __HIP_MEMORY_SCOPE_AGENT) == g)
                        __builtin_amdgcn_s_sleep(2);
                    (void)__hip_atomic_load(gen, __ATOMIC_ACQUIRE, __HIP_MEMORY_SCOPE_AGENT);
                }
            }
            __syncthreads();
        }
    }
}

extern "C" void kernel_launch(void* const* d_in, const int* in_sizes, int n_in,
                              void* d_out, int out_size, void* d_ws, size_t ws_size,
                              hipStream_t stream)
{
    const float* x   = (const float*)d_in[0];
    // d_in[1] = hidden_state (zeros, unused: every chunk starts from 0)
    const float* Wih = (const float*)d_in[2];
    const float* Whh = (const float*)d_in[3];
    const float* bih = (const float*)d_in[4];
    const float* bhh = (const float*)d_in[5];
    float* out = (float*)d_out;

    char* ws = (char*)d_ws;
    uint16_t* wih_bf = (uint16_t*)(ws);
    uint16_t* whh_bf = (uint16_t*)(ws + (size_t)(2<<20));
    uint16_t* hb0    = (uint16_t*)(ws + (size_t)(4<<20));
    uint16_t* hb1    = (uint16_t*)(ws + (size_t)(6<<20));
    float*    bias   = (float*)(ws + (size_t)(8<<20));
    unsigned* bar    = (unsigned*)(ws + (size_t)(8<<20) + 4096);

    prep_kernel<<<4096, 256, 0, stream>>>(Wih, Whh, bih, bhh, wih_bf, whh_bf, hb0, bias, bar);
    xproj_kernel<<<dim3(8, 1024), 256, 0, stream>>>(x, wih_bf, bias, out);

    void* args[] = { (void*)&whh_bf, (void*)&hb0, (void*)&hb1, (void*)&out, (void*)&bar };
    hipLaunchCooperativeKernel(scan_kernel, dim3(256), dim3(256), args, 0, stream);
}